// Round 3
// baseline (561.445 us; speedup 1.0000x reference)
//
#include <hip/hip_runtime.h>
#include <cstdint>
#include <cstddef>

// Fused LN + QKV + 4-token/2-head attention + out-proj + residual, MI355X.
// R5: occupancy/overlap round.
//  - ROWS 32->16, block 512->256 (4 waves): LDS 132.6 -> ~67 KB => 2 blocks/CU.
//    Same per-wave MFMA work; two independent blocks overlap barrier drains.
//  - qkvf chunk-pad swizzle: col -> col + (col>>6)*4, stride 812 (==12 mod 32)
//    => P3 q/k/v reads hit distinct bank groups (was 4-way conflicted).
//  - precision structure unchanged from R3 (bf16-pair split, fp32 attention).

typedef __attribute__((ext_vector_type(8))) short short8;
typedef __attribute__((ext_vector_type(8))) unsigned short ushort8;
typedef __attribute__((ext_vector_type(4))) float floatx4;

#define DIM    256
#define HD     128
#define ROWS   16            // rows per block (4 groups x 4 tokens)
#define XN_S   264           // xn / O LDS row stride in shorts (256+8)
#define QKV_SF 812           // qkv fp32 LDS row stride in floats (768 + 11*4 pad)
#define NT_QKV 48            // 768/16 n-tiles
#define NT_OP  16            // 256/16 n-tiles
#define SCALE  0.08838834764831845f   // 128^-0.5

// bf16 hi/lo weights in MFMA B-fragment order: [nt][k][lane][8]
__device__ unsigned short g_qkvw_hi[NT_QKV * 8 * 64 * 8];
__device__ unsigned short g_qkvw_lo[NT_QKV * 8 * 64 * 8];
__device__ unsigned short g_outw_hi[NT_OP * 8 * 64 * 8];
__device__ unsigned short g_outw_lo[NT_OP * 8 * 64 * 8];

__device__ __forceinline__ unsigned short f2bf(float f) {
  unsigned int u = __builtin_bit_cast(unsigned int, f);
  u += 0x7fffu + ((u >> 16) & 1u);          // RNE
  return (unsigned short)(u >> 16);
}
__device__ __forceinline__ float bf2f(unsigned short h) {
  return __builtin_bit_cast(float, (unsigned int)h << 16);
}
// qkv LDS column swizzle: +4 floats of pad per 64-float chunk
__device__ __forceinline__ int swz(int c) { return c + ((c >> 6) << 2); }

__global__ __launch_bounds__(256) void convert_weights(
    const float* __restrict__ qkv_w, const float* __restrict__ out_w) {
  const int id = blockIdx.x * 256 + threadIdx.x;   // 0..32767
  const float* src;
  unsigned short *dh, *dl;
  if (id < NT_QKV * 8 * 64) {
    const int nt = id >> 9, k = (id >> 6) & 7, lane = id & 63;
    src = qkv_w + (size_t)(nt * 16 + (lane & 15)) * DIM + k * 32 + (lane >> 4) * 8;
    dh = g_qkvw_hi + (size_t)id * 8;
    dl = g_qkvw_lo + (size_t)id * 8;
  } else {
    const int id2 = id - NT_QKV * 8 * 64;
    const int nt = id2 >> 9, k = (id2 >> 6) & 7, lane = id2 & 63;
    src = out_w + (size_t)(nt * 16 + (lane & 15)) * DIM + k * 32 + (lane >> 4) * 8;
    dh = g_outw_hi + (size_t)id2 * 8;
    dl = g_outw_lo + (size_t)id2 * 8;
  }
  float4 a = *reinterpret_cast<const float4*>(src);
  float4 b = *reinterpret_cast<const float4*>(src + 4);
  float f[8] = {a.x, a.y, a.z, a.w, b.x, b.y, b.z, b.w};
  ushort8 oh, ol;
#pragma unroll
  for (int e = 0; e < 8; ++e) {
    unsigned short h = f2bf(f[e]);
    oh[e] = h;
    ol[e] = f2bf(f[e] - bf2f(h));
  }
  *reinterpret_cast<ushort8*>(dh) = oh;
  *reinterpret_cast<ushort8*>(dl) = ol;
}

__global__ __launch_bounds__(256, 2) void fused_group_attn(
    const float* __restrict__ x,
    const float* __restrict__ qkv_b, const float* __restrict__ out_b,
    const float* __restrict__ ln_g, const float* __restrict__ ln_b,
    float* __restrict__ out) {
  __shared__ __align__(16) unsigned short xn_hi[ROWS * XN_S]; // LN hi; reused O hi
  __shared__ __align__(16) unsigned short xn_lo[ROWS * XN_S]; // LN lo; reused O lo
  __shared__ __align__(16) float qkvf[ROWS * QKV_SF];         // q|k|v fp32 (swizzled)

  const int tid  = threadIdx.x;
  const int lane = tid & 63;
  const int wid  = tid >> 6;          // 0..3
  const int quad = lane >> 4;         // 0..3
  const int l15  = lane & 15;
  const size_t rowbase = (size_t)blockIdx.x * ROWS;

  // ---------- P1: load x, LayerNorm -> xn hi/lo (bf16 pair) ----------
  {
    const int row = tid >> 4;         // 0..15 (16 threads per row)
    const int seg = tid & 15;         // 16 cols each
    const float4* xr4 = reinterpret_cast<const float4*>(
        x + (rowbase + row) * DIM + seg * 16);
    float4 v[4];
    float s = 0.f, sq = 0.f;
#pragma unroll
    for (int i = 0; i < 4; ++i) {
      v[i] = xr4[i];
      s  += v[i].x + v[i].y + v[i].z + v[i].w;
      sq += v[i].x * v[i].x + v[i].y * v[i].y + v[i].z * v[i].z + v[i].w * v[i].w;
    }
#pragma unroll
    for (int off = 1; off < 16; off <<= 1) {
      s  += __shfl_xor(s, off);
      sq += __shfl_xor(sq, off);
    }
    const float mu   = s * (1.f / DIM);
    const float var  = sq * (1.f / DIM) - mu * mu;
    const float rstd = rsqrtf(var + 1e-5f);
    const float4* g4 = reinterpret_cast<const float4*>(ln_g + seg * 16);
    const float4* b4 = reinterpret_cast<const float4*>(ln_b + seg * 16);
#pragma unroll
    for (int p = 0; p < 2; ++p) {
      float4 ga = g4[2 * p], gb = g4[2 * p + 1];
      float4 ba = b4[2 * p], bb = b4[2 * p + 1];
      float4 va = v[2 * p],  vb = v[2 * p + 1];
      float n[8] = {
        (va.x - mu) * rstd * ga.x + ba.x, (va.y - mu) * rstd * ga.y + ba.y,
        (va.z - mu) * rstd * ga.z + ba.z, (va.w - mu) * rstd * ga.w + ba.w,
        (vb.x - mu) * rstd * gb.x + bb.x, (vb.y - mu) * rstd * gb.y + bb.y,
        (vb.z - mu) * rstd * gb.z + bb.z, (vb.w - mu) * rstd * gb.w + bb.w};
      ushort8 oh, ol;
#pragma unroll
      for (int e = 0; e < 8; ++e) {
        unsigned short h = f2bf(n[e]);
        oh[e] = h;
        ol[e] = f2bf(n[e] - bf2f(h));
      }
      *reinterpret_cast<ushort8*>(&xn_hi[row * XN_S + seg * 16 + p * 8]) = oh;
      *reinterpret_cast<ushort8*>(&xn_lo[row * XN_S + seg * 16 + p * 8]) = ol;
    }
  }
  __syncthreads();

  // ---------- P2: QKV GEMM, 3-term split MFMA -> qkvf fp32 (swizzled) ----------
  {
    floatx4 acc[12];
#pragma unroll
    for (int n = 0; n < 12; ++n) acc[n] = (floatx4){0.f, 0.f, 0.f, 0.f};
#pragma unroll
    for (int k = 0; k < 8; ++k) {
      const int aoff = k * 32 + quad * 8;
      short8 ah = *reinterpret_cast<const short8*>(&xn_hi[l15 * XN_S + aoff]);
      short8 al = *reinterpret_cast<const short8*>(&xn_lo[l15 * XN_S + aoff]);
#pragma unroll
      for (int n = 0; n < 12; ++n) {
        const int boff = (((wid * 12 + n) * 8 + k) * 64 + lane) * 8;
        short8 bh = *reinterpret_cast<const short8*>(g_qkvw_hi + boff);
        short8 bl = *reinterpret_cast<const short8*>(g_qkvw_lo + boff);
        acc[n] = __builtin_amdgcn_mfma_f32_16x16x32_bf16(ah, bh, acc[n], 0, 0, 0);
        acc[n] = __builtin_amdgcn_mfma_f32_16x16x32_bf16(al, bh, acc[n], 0, 0, 0);
        acc[n] = __builtin_amdgcn_mfma_f32_16x16x32_bf16(ah, bl, acc[n], 0, 0, 0);
      }
    }
#pragma unroll
    for (int n = 0; n < 12; ++n) {
      const int col = (wid * 12 + n) * 16 + l15;
      const int scol = swz(col);      // 16 cols per n-tile never straddle a chunk
      const float bias = qkv_b[col];
#pragma unroll
      for (int r = 0; r < 4; ++r)
        qkvf[(quad * 4 + r) * QKV_SF + scol] = acc[n][r] + bias;
    }
  }
  __syncthreads();

  // ---------- P3: attention (fp32), one group per wave; lanes split by head ----------
  {
    const int g    = wid;             // group 0..3 (rows 4g..4g+3)
    const int half = lane >> 5;       // head
    const int l5   = lane & 31;
    const int t = (l5 & 15) >> 2, u = l5 & 3, c = l5 >> 4;
    const float4* qp = reinterpret_cast<const float4*>(
        &qkvf[(4 * g + t) * QKV_SF + swz(half * HD + c * 64)]);
    const float4* kp = reinterpret_cast<const float4*>(
        &qkvf[(4 * g + u) * QKV_SF + swz(256 + half * HD + c * 64)]);
    float sdot = 0.f;
#pragma unroll
    for (int j = 0; j < 16; ++j) {
      float4 qv = qp[j];
      float4 kv = kp[j];
      sdot += qv.x * kv.x + qv.y * kv.y + qv.z * kv.z + qv.w * kv.w;
    }
    sdot += __shfl_xor(sdot, 16);     // combine the two 64-elem chunks
    sdot *= SCALE;
    float mx = fmaxf(sdot, __shfl_xor(sdot, 1));
    mx = fmaxf(mx, __shfl_xor(mx, 2));
    float ex = __expf(sdot - mx);
    float den = ex + __shfl_xor(ex, 1);
    den += __shfl_xor(den, 2);
    const float p = ex / den;         // P[t][u] replicated on c=0/1

    // PV: t2 = l5>>3, 16-col segment per lane
    const int t2 = l5 >> 3, dseg = l5 & 7;
    float o[16];
#pragma unroll
    for (int e = 0; e < 16; ++e) o[e] = 0.f;
#pragma unroll
    for (int uu = 0; uu < 4; ++uu) {
      const float pu = __shfl(p, (lane & 32) + t2 * 4 + uu);
      const float4* vp = reinterpret_cast<const float4*>(
          &qkvf[(4 * g + uu) * QKV_SF + swz(512 + half * HD + dseg * 16)]);
      float4 v0 = vp[0], v1 = vp[1], v2 = vp[2], v3 = vp[3];
      o[0]  += pu * v0.x; o[1]  += pu * v0.y; o[2]  += pu * v0.z; o[3]  += pu * v0.w;
      o[4]  += pu * v1.x; o[5]  += pu * v1.y; o[6]  += pu * v1.z; o[7]  += pu * v1.w;
      o[8]  += pu * v2.x; o[9]  += pu * v2.y; o[10] += pu * v2.z; o[11] += pu * v2.w;
      o[12] += pu * v3.x; o[13] += pu * v3.y; o[14] += pu * v3.z; o[15] += pu * v3.w;
    }
    ushort8 h0, h1, l0, l1;
#pragma unroll
    for (int e = 0; e < 8; ++e) {
      unsigned short ha = f2bf(o[e]);
      h0[e] = ha; l0[e] = f2bf(o[e] - bf2f(ha));
      unsigned short hb = f2bf(o[e + 8]);
      h1[e] = hb; l1[e] = f2bf(o[e + 8] - bf2f(hb));
    }
    const int ooff = (4 * g + t2) * XN_S + half * HD + dseg * 16;
    *reinterpret_cast<ushort8*>(&xn_hi[ooff])     = h0;
    *reinterpret_cast<ushort8*>(&xn_hi[ooff + 8]) = h1;
    *reinterpret_cast<ushort8*>(&xn_lo[ooff])     = l0;
    *reinterpret_cast<ushort8*>(&xn_lo[ooff + 8]) = l1;
  }
  __syncthreads();

  // ---------- P4: out-proj GEMM (3-term split) + bias + residual ----------
  {
    floatx4 acc[4];
#pragma unroll
    for (int n = 0; n < 4; ++n) acc[n] = (floatx4){0.f, 0.f, 0.f, 0.f};
#pragma unroll
    for (int k = 0; k < 8; ++k) {
      const int aoff = k * 32 + quad * 8;
      short8 ah = *reinterpret_cast<const short8*>(&xn_hi[l15 * XN_S + aoff]);
      short8 al = *reinterpret_cast<const short8*>(&xn_lo[l15 * XN_S + aoff]);
#pragma unroll
      for (int n = 0; n < 4; ++n) {
        const int boff = (((wid * 4 + n) * 8 + k) * 64 + lane) * 8;
        short8 bh = *reinterpret_cast<const short8*>(g_outw_hi + boff);
        short8 bl = *reinterpret_cast<const short8*>(g_outw_lo + boff);
        acc[n] = __builtin_amdgcn_mfma_f32_16x16x32_bf16(ah, bh, acc[n], 0, 0, 0);
        acc[n] = __builtin_amdgcn_mfma_f32_16x16x32_bf16(al, bh, acc[n], 0, 0, 0);
        acc[n] = __builtin_amdgcn_mfma_f32_16x16x32_bf16(ah, bl, acc[n], 0, 0, 0);
      }
    }
#pragma unroll
    for (int n = 0; n < 4; ++n) {
      const int col = (wid * 4 + n) * 16 + l15;
      const float bias = out_b[col];
#pragma unroll
      for (int r = 0; r < 4; ++r) {
        const size_t gidx = (rowbase + quad * 4 + r) * DIM + col;
        out[gidx] = acc[n][r] + bias + x[gidx];
      }
    }
  }
}

extern "C" void kernel_launch(void* const* d_in, const int* in_sizes, int n_in,
                              void* d_out, int out_size, void* d_ws, size_t ws_size,
                              hipStream_t stream) {
  const float* x     = (const float*)d_in[0];
  const float* qkv_w = (const float*)d_in[1];
  const float* qkv_b = (const float*)d_in[2];
  const float* out_w = (const float*)d_in[3];
  const float* out_b = (const float*)d_in[4];
  const float* ln_g  = (const float*)d_in[5];
  const float* ln_b  = (const float*)d_in[6];
  float* out = (float*)d_out;

  hipLaunchKernelGGL(convert_weights, dim3(128), dim3(256), 0, stream, qkv_w, out_w);

  const int rows = in_sizes[0] / DIM;     // 131072
  const int nblk = rows / ROWS;           // 8192
  hipLaunchKernelGGL(fused_group_attn, dim3(nblk), dim3(256), 0, stream,
                     x, qkv_b, out_b, ln_g, ln_b, out);
}

// Round 4
// 459.071 us; speedup vs baseline: 1.2230x; 1.2230x over previous
//
#include <hip/hip_runtime.h>
#include <cstdint>
#include <cstddef>

// Fused LN + QKV + 4-token/2-head attention + out-proj + residual, MI355X.
// R6: L2-weight-traffic round.
//  - Post-mortem R5: per-CU L2 BW on weight B-fragments is the dominant cost
//    (2 MB/block @ 16x16x32, ~37k of 56k cycles/block). ROWS=16 doubled it.
//  - Back to ROWS=32 / 512 threads / 8 waves / 1 block/CU (R2 geometry).
//  - P2/P4 now use mfma_f32_32x32x16_bf16: 32 FLOP/B-byte (2x) -> 1 MB/block.
//  - qkvf keeps R5's chunk-pad swizzle (verified): col+=(col>>6)*4, stride 812.
//  - Precision structure unchanged (bf16-pair split, fp32 attention).

typedef __attribute__((ext_vector_type(8))) short short8;
typedef __attribute__((ext_vector_type(8))) unsigned short ushort8;
typedef __attribute__((ext_vector_type(16))) float floatx16;

#define DIM    256
#define HD     128
#define ROWS   32            // rows per block (8 groups x 4 tokens)
#define XN_S   264           // xn / O LDS row stride in shorts (256+8)
#define QKV_SF 812           // qkv fp32 LDS row stride in floats (768 + 11*4 pad)
#define NT32_QKV 24          // 768/32 n-tiles (32-wide)
#define NT32_OP  8           // 256/32 n-tiles
#define KS16     16          // 256/16 k-steps
#define SCALE  0.08838834764831845f   // 128^-0.5

// bf16 hi/lo weights in 32x32x16 MFMA B-fragment order: [nt][ks][lane][8]
// B[k][col]: col = nt*32 + (lane&31), k = ks*16 + (lane>>5)*8 + j
__device__ unsigned short g_qkvw_hi[NT32_QKV * KS16 * 64 * 8];   // 196608
__device__ unsigned short g_qkvw_lo[NT32_QKV * KS16 * 64 * 8];
__device__ unsigned short g_outw_hi[NT32_OP * KS16 * 64 * 8];    //  65536
__device__ unsigned short g_outw_lo[NT32_OP * KS16 * 64 * 8];

__device__ __forceinline__ unsigned short f2bf(float f) {
  unsigned int u = __builtin_bit_cast(unsigned int, f);
  u += 0x7fffu + ((u >> 16) & 1u);          // RNE
  return (unsigned short)(u >> 16);
}
__device__ __forceinline__ float bf2f(unsigned short h) {
  return __builtin_bit_cast(float, (unsigned int)h << 16);
}
// qkv LDS column swizzle: +4 floats of pad per 64-float chunk
__device__ __forceinline__ int swz(int c) { return c + ((c >> 6) << 2); }

__global__ __launch_bounds__(256) void convert_weights(
    const float* __restrict__ qkv_w, const float* __restrict__ out_w) {
  const int id = blockIdx.x * 256 + threadIdx.x;   // 0..32767
  const float* src;
  unsigned short *dh, *dl;
  if (id < NT32_QKV * KS16 * 64) {                 // 24576 qkv fragment rows
    const int nt = id >> 10, ks = (id >> 6) & 15, lane = id & 63;
    src = qkv_w + (size_t)(nt * 32 + (lane & 31)) * DIM + ks * 16 + (lane >> 5) * 8;
    dh = g_qkvw_hi + (size_t)id * 8;
    dl = g_qkvw_lo + (size_t)id * 8;
  } else {
    const int id2 = id - NT32_QKV * KS16 * 64;     // 8192 out fragment rows
    const int nt = id2 >> 10, ks = (id2 >> 6) & 15, lane = id2 & 63;
    src = out_w + (size_t)(nt * 32 + (lane & 31)) * DIM + ks * 16 + (lane >> 5) * 8;
    dh = g_outw_hi + (size_t)id2 * 8;
    dl = g_outw_lo + (size_t)id2 * 8;
  }
  float4 a = *reinterpret_cast<const float4*>(src);
  float4 b = *reinterpret_cast<const float4*>(src + 4);
  float f[8] = {a.x, a.y, a.z, a.w, b.x, b.y, b.z, b.w};
  ushort8 oh, ol;
#pragma unroll
  for (int e = 0; e < 8; ++e) {
    unsigned short h = f2bf(f[e]);
    oh[e] = h;
    ol[e] = f2bf(f[e] - bf2f(h));
  }
  *reinterpret_cast<ushort8*>(dh) = oh;
  *reinterpret_cast<ushort8*>(dl) = ol;
}

__global__ __launch_bounds__(512, 2) void fused_group_attn(
    const float* __restrict__ x,
    const float* __restrict__ qkv_b, const float* __restrict__ out_b,
    const float* __restrict__ ln_g, const float* __restrict__ ln_b,
    float* __restrict__ out) {
  __shared__ __align__(16) unsigned short xn_hi[ROWS * XN_S]; // LN hi; reused O hi
  __shared__ __align__(16) unsigned short xn_lo[ROWS * XN_S]; // LN lo; reused O lo
  __shared__ __align__(16) float qkvf[ROWS * QKV_SF];         // q|k|v fp32 (swizzled)

  const int tid  = threadIdx.x;
  const int lane = tid & 63;
  const int wid  = tid >> 6;          // 0..7
  const int l31  = lane & 31;
  const int khalf = lane >> 5;        // 0/1: k-subgroup for 32x32x16 A/B frags
  const size_t rowbase = (size_t)blockIdx.x * ROWS;

  // ---------- P1: load x, LayerNorm -> xn hi/lo (bf16 pair) ----------
  {
    const int row = tid >> 4;         // 0..31 (16 threads per row)
    const int seg = tid & 15;         // 16 cols each
    const float4* xr4 = reinterpret_cast<const float4*>(
        x + (rowbase + row) * DIM + seg * 16);
    float4 v[4];
    float s = 0.f, sq = 0.f;
#pragma unroll
    for (int i = 0; i < 4; ++i) {
      v[i] = xr4[i];
      s  += v[i].x + v[i].y + v[i].z + v[i].w;
      sq += v[i].x * v[i].x + v[i].y * v[i].y + v[i].z * v[i].z + v[i].w * v[i].w;
    }
#pragma unroll
    for (int off = 1; off < 16; off <<= 1) {
      s  += __shfl_xor(s, off);
      sq += __shfl_xor(sq, off);
    }
    const float mu   = s * (1.f / DIM);
    const float var  = sq * (1.f / DIM) - mu * mu;
    const float rstd = rsqrtf(var + 1e-5f);
    const float4* g4 = reinterpret_cast<const float4*>(ln_g + seg * 16);
    const float4* b4 = reinterpret_cast<const float4*>(ln_b + seg * 16);
#pragma unroll
    for (int p = 0; p < 2; ++p) {
      float4 ga = g4[2 * p], gb = g4[2 * p + 1];
      float4 ba = b4[2 * p], bb = b4[2 * p + 1];
      float4 va = v[2 * p],  vb = v[2 * p + 1];
      float n[8] = {
        (va.x - mu) * rstd * ga.x + ba.x, (va.y - mu) * rstd * ga.y + ba.y,
        (va.z - mu) * rstd * ga.z + ba.z, (va.w - mu) * rstd * ga.w + ba.w,
        (vb.x - mu) * rstd * gb.x + bb.x, (vb.y - mu) * rstd * gb.y + bb.y,
        (vb.z - mu) * rstd * gb.z + bb.z, (vb.w - mu) * rstd * gb.w + bb.w};
      ushort8 oh, ol;
#pragma unroll
      for (int e = 0; e < 8; ++e) {
        unsigned short h = f2bf(n[e]);
        oh[e] = h;
        ol[e] = f2bf(n[e] - bf2f(h));
      }
      *reinterpret_cast<ushort8*>(&xn_hi[row * XN_S + seg * 16 + p * 8]) = oh;
      *reinterpret_cast<ushort8*>(&xn_lo[row * XN_S + seg * 16 + p * 8]) = ol;
    }
  }
  __syncthreads();

  // ---------- P2: QKV GEMM 32x32x16, 3-term split -> qkvf fp32 (swizzled) ----------
  {
    floatx16 acc[3];
#pragma unroll
    for (int n = 0; n < 3; ++n)
#pragma unroll
      for (int i = 0; i < 16; ++i) acc[n][i] = 0.f;
#pragma unroll
    for (int ks = 0; ks < KS16; ++ks) {
      const int aoff = ks * 16 + khalf * 8;
      short8 ah = *reinterpret_cast<const short8*>(&xn_hi[l31 * XN_S + aoff]);
      short8 al = *reinterpret_cast<const short8*>(&xn_lo[l31 * XN_S + aoff]);
#pragma unroll
      for (int n = 0; n < 3; ++n) {
        const int boff = (((wid * 3 + n) * KS16 + ks) * 64 + lane) * 8;
        short8 bh = *reinterpret_cast<const short8*>(g_qkvw_hi + boff);
        short8 bl = *reinterpret_cast<const short8*>(g_qkvw_lo + boff);
        acc[n] = __builtin_amdgcn_mfma_f32_32x32x16_bf16(ah, bh, acc[n], 0, 0, 0);
        acc[n] = __builtin_amdgcn_mfma_f32_32x32x16_bf16(al, bh, acc[n], 0, 0, 0);
        acc[n] = __builtin_amdgcn_mfma_f32_32x32x16_bf16(ah, bl, acc[n], 0, 0, 0);
      }
    }
#pragma unroll
    for (int n = 0; n < 3; ++n) {
      const int col = (wid * 3 + n) * 32 + l31;
      const int scol = swz(col);
      const float bias = qkv_b[col];
#pragma unroll
      for (int i = 0; i < 16; ++i) {
        const int row = (i & 3) + 8 * (i >> 2) + 4 * khalf;
        qkvf[row * QKV_SF + scol] = acc[n][i] + bias;
      }
    }
  }
  __syncthreads();

  // ---------- P3: attention (fp32), one group per wave; lanes split by head ----------
  {
    const int g    = wid;             // group 0..7 (rows 4g..4g+3)
    const int half = lane >> 5;       // head
    const int l5   = lane & 31;
    const int t = (l5 & 15) >> 2, u = l5 & 3, c = l5 >> 4;
    const float4* qp = reinterpret_cast<const float4*>(
        &qkvf[(4 * g + t) * QKV_SF + swz(half * HD + c * 64)]);
    const float4* kp = reinterpret_cast<const float4*>(
        &qkvf[(4 * g + u) * QKV_SF + swz(256 + half * HD + c * 64)]);
    float sdot = 0.f;
#pragma unroll
    for (int j = 0; j < 16; ++j) {
      float4 qv = qp[j];
      float4 kv = kp[j];
      sdot += qv.x * kv.x + qv.y * kv.y + qv.z * kv.z + qv.w * kv.w;
    }
    sdot += __shfl_xor(sdot, 16);     // combine the two 64-elem chunks
    sdot *= SCALE;
    float mx = fmaxf(sdot, __shfl_xor(sdot, 1));
    mx = fmaxf(mx, __shfl_xor(mx, 2));
    float ex = __expf(sdot - mx);
    float den = ex + __shfl_xor(ex, 1);
    den += __shfl_xor(den, 2);
    const float p = ex / den;         // P[t][u] replicated on c=0/1

    // PV: t2 = l5>>3, 16-col segment per lane
    const int t2 = l5 >> 3, dseg = l5 & 7;
    float o[16];
#pragma unroll
    for (int e = 0; e < 16; ++e) o[e] = 0.f;
#pragma unroll
    for (int uu = 0; uu < 4; ++uu) {
      const float pu = __shfl(p, (lane & 32) + t2 * 4 + uu);
      const float4* vp = reinterpret_cast<const float4*>(
          &qkvf[(4 * g + uu) * QKV_SF + swz(512 + half * HD + dseg * 16)]);
      float4 v0 = vp[0], v1 = vp[1], v2 = vp[2], v3 = vp[3];
      o[0]  += pu * v0.x; o[1]  += pu * v0.y; o[2]  += pu * v0.z; o[3]  += pu * v0.w;
      o[4]  += pu * v1.x; o[5]  += pu * v1.y; o[6]  += pu * v1.z; o[7]  += pu * v1.w;
      o[8]  += pu * v2.x; o[9]  += pu * v2.y; o[10] += pu * v2.z; o[11] += pu * v2.w;
      o[12] += pu * v3.x; o[13] += pu * v3.y; o[14] += pu * v3.z; o[15] += pu * v3.w;
    }
    ushort8 h0, h1, l0, l1;
#pragma unroll
    for (int e = 0; e < 8; ++e) {
      unsigned short ha = f2bf(o[e]);
      h0[e] = ha; l0[e] = f2bf(o[e] - bf2f(ha));
      unsigned short hb = f2bf(o[e + 8]);
      h1[e] = hb; l1[e] = f2bf(o[e + 8] - bf2f(hb));
    }
    const int ooff = (4 * g + t2) * XN_S + half * HD + dseg * 16;
    *reinterpret_cast<ushort8*>(&xn_hi[ooff])     = h0;
    *reinterpret_cast<ushort8*>(&xn_hi[ooff + 8]) = h1;
    *reinterpret_cast<ushort8*>(&xn_lo[ooff])     = l0;
    *reinterpret_cast<ushort8*>(&xn_lo[ooff + 8]) = l1;
  }
  __syncthreads();

  // ---------- P4: out-proj GEMM 32x32x16 (3-term split) + bias + residual ----------
  {
    floatx16 acc;
#pragma unroll
    for (int i = 0; i < 16; ++i) acc[i] = 0.f;
#pragma unroll
    for (int ks = 0; ks < KS16; ++ks) {
      const int aoff = ks * 16 + khalf * 8;
      short8 ah = *reinterpret_cast<const short8*>(&xn_hi[l31 * XN_S + aoff]);
      short8 al = *reinterpret_cast<const short8*>(&xn_lo[l31 * XN_S + aoff]);
      const int boff = ((wid * KS16 + ks) * 64 + lane) * 8;
      short8 bh = *reinterpret_cast<const short8*>(g_outw_hi + boff);
      short8 bl = *reinterpret_cast<const short8*>(g_outw_lo + boff);
      acc = __builtin_amdgcn_mfma_f32_32x32x16_bf16(ah, bh, acc, 0, 0, 0);
      acc = __builtin_amdgcn_mfma_f32_32x32x16_bf16(al, bh, acc, 0, 0, 0);
      acc = __builtin_amdgcn_mfma_f32_32x32x16_bf16(ah, bl, acc, 0, 0, 0);
    }
    const int col = wid * 32 + l31;
    const float bias = out_b[col];
#pragma unroll
    for (int i = 0; i < 16; ++i) {
      const int row = (i & 3) + 8 * (i >> 2) + 4 * khalf;
      const size_t gidx = (rowbase + row) * DIM + col;
      out[gidx] = acc[i] + bias + x[gidx];
    }
  }
}

extern "C" void kernel_launch(void* const* d_in, const int* in_sizes, int n_in,
                              void* d_out, int out_size, void* d_ws, size_t ws_size,
                              hipStream_t stream) {
  const float* x     = (const float*)d_in[0];
  const float* qkv_w = (const float*)d_in[1];
  const float* qkv_b = (const float*)d_in[2];
  const float* out_w = (const float*)d_in[3];
  const float* out_b = (const float*)d_in[4];
  const float* ln_g  = (const float*)d_in[5];
  const float* ln_b  = (const float*)d_in[6];
  float* out = (float*)d_out;

  hipLaunchKernelGGL(convert_weights, dim3(128), dim3(256), 0, stream, qkv_w, out_w);

  const int rows = in_sizes[0] / DIM;     // 131072
  const int nblk = rows / ROWS;           // 4096
  hipLaunchKernelGGL(fused_group_attn, dim3(nblk), dim3(512), 0, stream,
                     x, qkv_b, out_b, ln_g, ln_b, out);
}

// Round 5
// 362.568 us; speedup vs baseline: 1.5485x; 1.2662x over previous
//
#include <hip/hip_runtime.h>
#include <cstdint>
#include <cstddef>

// Fused LN + QKV + 4-token/2-head attention + out-proj + residual, MI355X.
// R7: cut both dominant per-block costs (L2 weight bytes + MFMA issue slots).
//  - Post-mortem R6: MfmaUtil ~= % of peak FLOPs => 32x32x16 MFMA = ~32
//    SIMD-issue cyc; 3-term split cost 12.4k cyc/block (25%). L2 weight
//    stream (hi+lo, 1.05 MB/block) ~18.7k cyc. Both scale with B-planes.
//  - B-weights now single bf16 (hi only): error budget allows it (score path
//    q/k/v stays fp32 in LDS; A-side keeps hi/lo split). 2-term MFMA AhB+AlB.
//  - P4 B-fragments prefetched into registers before P3 (hidden under P3).
//  - Geometry unchanged from R6: ROWS=32, 512 thr, 32x32x16, qkvf swizzle.

typedef __attribute__((ext_vector_type(8))) short short8;
typedef __attribute__((ext_vector_type(8))) unsigned short ushort8;
typedef __attribute__((ext_vector_type(16))) float floatx16;

#define DIM    256
#define HD     128
#define ROWS   32            // rows per block (8 groups x 4 tokens)
#define XN_S   264           // xn / O LDS row stride in shorts (256+8)
#define QKV_SF 812           // qkv fp32 LDS row stride in floats (768 + 11*4 pad)
#define NT32_QKV 24          // 768/32 n-tiles (32-wide)
#define NT32_OP  8           // 256/32 n-tiles
#define KS16     16          // 256/16 k-steps
#define SCALE  0.08838834764831845f   // 128^-0.5

// bf16 weights in 32x32x16 MFMA B-fragment order: [nt][ks][lane][8]
// B[k][col]: col = nt*32 + (lane&31), k = ks*16 + (lane>>5)*8 + j
__device__ unsigned short g_qkvw[NT32_QKV * KS16 * 64 * 8];   // 196608
__device__ unsigned short g_outw[NT32_OP * KS16 * 64 * 8];    //  65536

__device__ __forceinline__ unsigned short f2bf(float f) {
  unsigned int u = __builtin_bit_cast(unsigned int, f);
  u += 0x7fffu + ((u >> 16) & 1u);          // RNE
  return (unsigned short)(u >> 16);
}
__device__ __forceinline__ float bf2f(unsigned short h) {
  return __builtin_bit_cast(float, (unsigned int)h << 16);
}
// qkv LDS column swizzle: +4 floats of pad per 64-float chunk
__device__ __forceinline__ int swz(int c) { return c + ((c >> 6) << 2); }

__global__ __launch_bounds__(256) void convert_weights(
    const float* __restrict__ qkv_w, const float* __restrict__ out_w) {
  const int id = blockIdx.x * 256 + threadIdx.x;   // 0..32767
  const float* src;
  unsigned short* dh;
  if (id < NT32_QKV * KS16 * 64) {                 // 24576 qkv fragment rows
    const int nt = id >> 10, ks = (id >> 6) & 15, lane = id & 63;
    src = qkv_w + (size_t)(nt * 32 + (lane & 31)) * DIM + ks * 16 + (lane >> 5) * 8;
    dh = g_qkvw + (size_t)id * 8;
  } else {
    const int id2 = id - NT32_QKV * KS16 * 64;     // 8192 out fragment rows
    const int nt = id2 >> 10, ks = (id2 >> 6) & 15, lane = id2 & 63;
    src = out_w + (size_t)(nt * 32 + (lane & 31)) * DIM + ks * 16 + (lane >> 5) * 8;
    dh = g_outw + (size_t)id2 * 8;
  }
  float4 a = *reinterpret_cast<const float4*>(src);
  float4 b = *reinterpret_cast<const float4*>(src + 4);
  ushort8 oh;
  oh[0] = f2bf(a.x); oh[1] = f2bf(a.y); oh[2] = f2bf(a.z); oh[3] = f2bf(a.w);
  oh[4] = f2bf(b.x); oh[5] = f2bf(b.y); oh[6] = f2bf(b.z); oh[7] = f2bf(b.w);
  *reinterpret_cast<ushort8*>(dh) = oh;
}

__global__ __launch_bounds__(512, 2) void fused_group_attn(
    const float* __restrict__ x,
    const float* __restrict__ qkv_b, const float* __restrict__ out_b,
    const float* __restrict__ ln_g, const float* __restrict__ ln_b,
    float* __restrict__ out) {
  __shared__ __align__(16) unsigned short xn_hi[ROWS * XN_S]; // LN hi; reused O hi
  __shared__ __align__(16) unsigned short xn_lo[ROWS * XN_S]; // LN lo; reused O lo
  __shared__ __align__(16) float qkvf[ROWS * QKV_SF];         // q|k|v fp32 (swizzled)

  const int tid  = threadIdx.x;
  const int lane = tid & 63;
  const int wid  = tid >> 6;          // 0..7
  const int l31  = lane & 31;
  const int khalf = lane >> 5;        // 0/1: k-subgroup for 32x32x16 A/B frags
  const size_t rowbase = (size_t)blockIdx.x * ROWS;

  // ---------- P1: load x, LayerNorm -> xn hi/lo (bf16 pair) ----------
  {
    const int row = tid >> 4;         // 0..31 (16 threads per row)
    const int seg = tid & 15;         // 16 cols each
    const float4* xr4 = reinterpret_cast<const float4*>(
        x + (rowbase + row) * DIM + seg * 16);
    float4 v[4];
    float s = 0.f, sq = 0.f;
#pragma unroll
    for (int i = 0; i < 4; ++i) {
      v[i] = xr4[i];
      s  += v[i].x + v[i].y + v[i].z + v[i].w;
      sq += v[i].x * v[i].x + v[i].y * v[i].y + v[i].z * v[i].z + v[i].w * v[i].w;
    }
#pragma unroll
    for (int off = 1; off < 16; off <<= 1) {
      s  += __shfl_xor(s, off);
      sq += __shfl_xor(sq, off);
    }
    const float mu   = s * (1.f / DIM);
    const float var  = sq * (1.f / DIM) - mu * mu;
    const float rstd = rsqrtf(var + 1e-5f);
    const float4* g4 = reinterpret_cast<const float4*>(ln_g + seg * 16);
    const float4* b4 = reinterpret_cast<const float4*>(ln_b + seg * 16);
#pragma unroll
    for (int p = 0; p < 2; ++p) {
      float4 ga = g4[2 * p], gb = g4[2 * p + 1];
      float4 ba = b4[2 * p], bb = b4[2 * p + 1];
      float4 va = v[2 * p],  vb = v[2 * p + 1];
      float n[8] = {
        (va.x - mu) * rstd * ga.x + ba.x, (va.y - mu) * rstd * ga.y + ba.y,
        (va.z - mu) * rstd * ga.z + ba.z, (va.w - mu) * rstd * ga.w + ba.w,
        (vb.x - mu) * rstd * gb.x + bb.x, (vb.y - mu) * rstd * gb.y + bb.y,
        (vb.z - mu) * rstd * gb.z + bb.z, (vb.w - mu) * rstd * gb.w + bb.w};
      ushort8 oh, ol;
#pragma unroll
      for (int e = 0; e < 8; ++e) {
        unsigned short h = f2bf(n[e]);
        oh[e] = h;
        ol[e] = f2bf(n[e] - bf2f(h));
      }
      *reinterpret_cast<ushort8*>(&xn_hi[row * XN_S + seg * 16 + p * 8]) = oh;
      *reinterpret_cast<ushort8*>(&xn_lo[row * XN_S + seg * 16 + p * 8]) = ol;
    }
  }
  __syncthreads();

  // ---------- P2: QKV GEMM 32x32x16, 2-term split -> qkvf fp32 (swizzled) ----------
  {
    floatx16 acc[3];
#pragma unroll
    for (int n = 0; n < 3; ++n)
#pragma unroll
      for (int i = 0; i < 16; ++i) acc[n][i] = 0.f;
#pragma unroll
    for (int ks = 0; ks < KS16; ++ks) {
      const int aoff = ks * 16 + khalf * 8;
      short8 ah = *reinterpret_cast<const short8*>(&xn_hi[l31 * XN_S + aoff]);
      short8 al = *reinterpret_cast<const short8*>(&xn_lo[l31 * XN_S + aoff]);
#pragma unroll
      for (int n = 0; n < 3; ++n) {
        const int boff = (((wid * 3 + n) * KS16 + ks) * 64 + lane) * 8;
        short8 bh = *reinterpret_cast<const short8*>(g_qkvw + boff);
        acc[n] = __builtin_amdgcn_mfma_f32_32x32x16_bf16(ah, bh, acc[n], 0, 0, 0);
        acc[n] = __builtin_amdgcn_mfma_f32_32x32x16_bf16(al, bh, acc[n], 0, 0, 0);
      }
    }
#pragma unroll
    for (int n = 0; n < 3; ++n) {
      const int col = (wid * 3 + n) * 32 + l31;
      const int scol = swz(col);
      const float bias = qkv_b[col];
#pragma unroll
      for (int i = 0; i < 16; ++i) {
        const int row = (i & 3) + 8 * (i >> 2) + 4 * khalf;
        qkvf[row * QKV_SF + scol] = acc[n][i] + bias;
      }
    }
  }

  // ---------- P4 B-fragment prefetch (hidden under P3) ----------
  short8 pb[KS16];
#pragma unroll
  for (int ks = 0; ks < KS16; ++ks)
    pb[ks] = *reinterpret_cast<const short8*>(
        g_outw + (size_t)((wid * KS16 + ks) * 64 + lane) * 8);

  __syncthreads();

  // ---------- P3: attention (fp32), one group per wave; lanes split by head ----------
  {
    const int g    = wid;             // group 0..7 (rows 4g..4g+3)
    const int half = lane >> 5;       // head
    const int l5   = lane & 31;
    const int t = (l5 & 15) >> 2, u = l5 & 3, c = l5 >> 4;
    const float4* qp = reinterpret_cast<const float4*>(
        &qkvf[(4 * g + t) * QKV_SF + swz(half * HD + c * 64)]);
    const float4* kp = reinterpret_cast<const float4*>(
        &qkvf[(4 * g + u) * QKV_SF + swz(256 + half * HD + c * 64)]);
    float sdot = 0.f;
#pragma unroll
    for (int j = 0; j < 16; ++j) {
      float4 qv = qp[j];
      float4 kv = kp[j];
      sdot += qv.x * kv.x + qv.y * kv.y + qv.z * kv.z + qv.w * kv.w;
    }
    sdot += __shfl_xor(sdot, 16);     // combine the two 64-elem chunks
    sdot *= SCALE;
    float mx = fmaxf(sdot, __shfl_xor(sdot, 1));
    mx = fmaxf(mx, __shfl_xor(mx, 2));
    float ex = __expf(sdot - mx);
    float den = ex + __shfl_xor(ex, 1);
    den += __shfl_xor(den, 2);
    const float p = ex / den;         // P[t][u] replicated on c=0/1

    // PV: t2 = l5>>3, 16-col segment per lane
    const int t2 = l5 >> 3, dseg = l5 & 7;
    float o[16];
#pragma unroll
    for (int e = 0; e < 16; ++e) o[e] = 0.f;
#pragma unroll
    for (int uu = 0; uu < 4; ++uu) {
      const float pu = __shfl(p, (lane & 32) + t2 * 4 + uu);
      const float4* vp = reinterpret_cast<const float4*>(
          &qkvf[(4 * g + uu) * QKV_SF + swz(512 + half * HD + dseg * 16)]);
      float4 v0 = vp[0], v1 = vp[1], v2 = vp[2], v3 = vp[3];
      o[0]  += pu * v0.x; o[1]  += pu * v0.y; o[2]  += pu * v0.z; o[3]  += pu * v0.w;
      o[4]  += pu * v1.x; o[5]  += pu * v1.y; o[6]  += pu * v1.z; o[7]  += pu * v1.w;
      o[8]  += pu * v2.x; o[9]  += pu * v2.y; o[10] += pu * v2.z; o[11] += pu * v2.w;
      o[12] += pu * v3.x; o[13] += pu * v3.y; o[14] += pu * v3.z; o[15] += pu * v3.w;
    }
    ushort8 h0, h1, l0, l1;
#pragma unroll
    for (int e = 0; e < 8; ++e) {
      unsigned short ha = f2bf(o[e]);
      h0[e] = ha; l0[e] = f2bf(o[e] - bf2f(ha));
      unsigned short hb = f2bf(o[e + 8]);
      h1[e] = hb; l1[e] = f2bf(o[e + 8] - bf2f(hb));
    }
    const int ooff = (4 * g + t2) * XN_S + half * HD + dseg * 16;
    *reinterpret_cast<ushort8*>(&xn_hi[ooff])     = h0;
    *reinterpret_cast<ushort8*>(&xn_hi[ooff + 8]) = h1;
    *reinterpret_cast<ushort8*>(&xn_lo[ooff])     = l0;
    *reinterpret_cast<ushort8*>(&xn_lo[ooff + 8]) = l1;
  }
  __syncthreads();

  // ---------- P4: out-proj GEMM 32x32x16 (2-term, prefetched B) + residual ----------
  {
    floatx16 acc;
#pragma unroll
    for (int i = 0; i < 16; ++i) acc[i] = 0.f;
#pragma unroll
    for (int ks = 0; ks < KS16; ++ks) {
      const int aoff = ks * 16 + khalf * 8;
      short8 ah = *reinterpret_cast<const short8*>(&xn_hi[l31 * XN_S + aoff]);
      short8 al = *reinterpret_cast<const short8*>(&xn_lo[l31 * XN_S + aoff]);
      acc = __builtin_amdgcn_mfma_f32_32x32x16_bf16(ah, pb[ks], acc, 0, 0, 0);
      acc = __builtin_amdgcn_mfma_f32_32x32x16_bf16(al, pb[ks], acc, 0, 0, 0);
    }
    const int col = wid * 32 + l31;
    const float bias = out_b[col];
#pragma unroll
    for (int i = 0; i < 16; ++i) {
      const int row = (i & 3) + 8 * (i >> 2) + 4 * khalf;
      const size_t gidx = (rowbase + row) * DIM + col;
      out[gidx] = acc[i] + bias + x[gidx];
    }
  }
}

extern "C" void kernel_launch(void* const* d_in, const int* in_sizes, int n_in,
                              void* d_out, int out_size, void* d_ws, size_t ws_size,
                              hipStream_t stream) {
  const float* x     = (const float*)d_in[0];
  const float* qkv_w = (const float*)d_in[1];
  const float* qkv_b = (const float*)d_in[2];
  const float* out_w = (const float*)d_in[3];
  const float* out_b = (const float*)d_in[4];
  const float* ln_g  = (const float*)d_in[5];
  const float* ln_b  = (const float*)d_in[6];
  float* out = (float*)d_out;

  hipLaunchKernelGGL(convert_weights, dim3(128), dim3(256), 0, stream, qkv_w, out_w);

  const int rows = in_sizes[0] / DIM;     // 131072
  const int nblk = rows / ROWS;           // 4096
  hipLaunchKernelGGL(fused_group_attn, dim3(nblk), dim3(512), 0, stream,
                     x, qkv_b, out_b, ln_g, ln_b, out);
}